// Round 2
// baseline (748.671 us; speedup 1.0000x reference)
//
#include <hip/hip_runtime.h>
#include <hip/hip_bf16.h>
#include <stdint.h>

// Problem constants (from reference): B=4, S=2048, D_IN=D_OUT=4096
constexpr int M = 4 * 2048;   // 8192 tokens
constexpr int K = 4096;       // D_IN
constexpr int N = 4096;       // D_OUT
constexpr float EPSf = 1e-5f;
constexpr float QMAX = 127.0f;

typedef __attribute__((ext_vector_type(8))) short bf16x8;    // 8 bf16 (4 VGPRs)
typedef __attribute__((ext_vector_type(16))) float f32x16;   // 32x32 MFMA C/D

// bf16 round-to-nearest-even from f32 (no NaN inputs here)
__device__ __forceinline__ unsigned short f2bf(float f) {
  union { float f; uint32_t u; } c; c.f = f;
  uint32_t u = c.u;
  return (unsigned short)((u + 0x7fffu + ((u >> 16) & 1u)) >> 16);
}

__device__ __forceinline__ void async_copy16(const void* g, const void* l) {
  __builtin_amdgcn_global_load_lds(
      (const __attribute__((address_space(1))) unsigned int*)g,
      (__attribute__((address_space(3))) unsigned int*)l, 16, 0, 0);
}

// ---------------- Fused quant kernel ----------------
// Blocks [0, XBLOCKS): per-token per-group(64) absmax fake-quant of x -> bf16.
// Blocks [XBLOCKS, XBLOCKS+N): per-row ternary absmean quant of W -> bf16 {-1,0,1} + scale.
constexpr int XBLOCKS = (M * K / 4) / 256;   // 32768

__global__ void __launch_bounds__(256) quant_fused_kernel(
    const float* __restrict__ x, const float* __restrict__ w,
    unsigned short* __restrict__ xq, unsigned short* __restrict__ wt,
    float* __restrict__ wscale) {
  const int tid = threadIdx.x;
  if (blockIdx.x < XBLOCKS) {
    // ---- x quant: one float4 per thread; group of 64 = 16 consecutive lanes
    const int t = blockIdx.x * 256 + tid;
    const float4 v = ((const float4*)x)[t];
    float m = fmaxf(fmaxf(fabsf(v.x), fabsf(v.y)), fmaxf(fabsf(v.z), fabsf(v.w)));
    #pragma unroll
    for (int d = 1; d < 16; d <<= 1) m = fmaxf(m, __shfl_xor(m, d));
    m = fmaxf(m, EPSf);
    const float scale = QMAX / m;         // same op order as reference
    float q0 = fminf(fmaxf(rintf(v.x * scale), -QMAX), QMAX);
    float q1 = fminf(fmaxf(rintf(v.y * scale), -QMAX), QMAX);
    float q2 = fminf(fmaxf(rintf(v.z * scale), -QMAX), QMAX);
    float q3 = fminf(fmaxf(rintf(v.w * scale), -QMAX), QMAX);
    ushort4 o;
    o.x = f2bf(q0 / scale);
    o.y = f2bf(q1 / scale);
    o.z = f2bf(q2 / scale);
    o.w = f2bf(q3 / scale);
    ((ushort4*)xq)[t] = o;
  } else {
    // ---- w quant: one block per row of 4096
    const int row = blockIdx.x - XBLOCKS;
    const float* wr = w + (long)row * K;
    float4 v[4];
    float s = 0.f;
    #pragma unroll
    for (int p = 0; p < 4; p++) {
      v[p] = ((const float4*)wr)[tid + p * 256];
      s += fabsf(v[p].x) + fabsf(v[p].y) + fabsf(v[p].z) + fabsf(v[p].w);
    }
    #pragma unroll
    for (int d = 1; d < 64; d <<= 1) s += __shfl_xor(s, d);
    __shared__ float red[4];
    if ((tid & 63) == 0) red[tid >> 6] = s;
    __syncthreads();
    const float tot = red[0] + red[1] + red[2] + red[3];
    const float sc = fmaxf(tot / (float)K, EPSf);
    if (tid == 0) wscale[row] = sc;
    unsigned short* wrow = wt + (long)row * K;
    #pragma unroll
    for (int p = 0; p < 4; p++) {
      ushort4 o;
      o.x = f2bf(fminf(fmaxf(rintf(v[p].x / sc), -1.f), 1.f));  // {-1,0,1}: exact bf16
      o.y = f2bf(fminf(fmaxf(rintf(v[p].y / sc), -1.f), 1.f));
      o.z = f2bf(fminf(fmaxf(rintf(v[p].z / sc), -1.f), 1.f));
      o.w = f2bf(fminf(fmaxf(rintf(v[p].w / sc), -1.f), 1.f));
      ((ushort4*)wrow)[tid + p * 256] = o;
    }
  }
}

// ---------------- GEMM: C[M,N] = A[M,K] * T[N,K]^T, epilogue *wscale[n]
// 128x128 tile, BK=32, 4 waves x (2x2) mfma_f32_32x32x16_bf16,
// double-buffered LDS with one barrier per K-step, global_load_lds width=16.
//
// LDS layout per 128x32 tile (frag-group-major so 32x32 fragment reads are
// contiguous 1KB wave accesses): [rowblk 0..3][g=s*2+khalf 0..3][row 0..31][8 bf16]
// Staging thread tid covers (row = (tid&31)+(tid>>7)*32, col = ((tid>>5)&3)*8),
// LDS dst = tid*16B — satisfies global_load_lds lane-ordered destination rule.
__device__ __forceinline__ void stage_tile(const short* __restrict__ gsrc,
                                           short* __restrict__ lbase,
                                           int tid, int k0) {
  const int row = (tid & 31) + ((tid >> 7) << 5);   // 0..63
  const int col = ((tid >> 5) & 3) * 8;             // 0,8,16,24
  async_copy16(gsrc + (long)row * K + k0 + col, lbase + tid * 8);
  async_copy16(gsrc + (long)(row + 64) * K + k0 + col, lbase + 2048 + tid * 8);
}

__global__ void __launch_bounds__(256) gemm_bt_kernel(const short* __restrict__ A,
                                                      const short* __restrict__ Bt,
                                                      const float* __restrict__ wscale,
                                                      float* __restrict__ C) {
  __shared__ short sA[2][128 * 32];   // 2 x 8 KB
  __shared__ short sB[2][128 * 32];

  const int n0 = blockIdx.x * 128;
  const int m0 = blockIdx.y * 128;
  const int tid  = (int)threadIdx.x;
  const int lane = tid & 63;
  const int wv   = tid >> 6;
  const int wm = wv & 1, wn = wv >> 1;      // 2x2 waves -> 64x64 tile each
  const int ln = lane & 31;                 // row/col within 32x32 frag
  const int kh = lane >> 5;                 // k-half selector

  f32x16 acc[2][2];
  #pragma unroll
  for (int i = 0; i < 2; i++)
    #pragma unroll
    for (int j = 0; j < 2; j++)
      #pragma unroll
      for (int r = 0; r < 16; r++) acc[i][j][r] = 0.f;

  const short* Ab = A  + (long)m0 * K;
  const short* Bb = Bt + (long)n0 * K;

  // fragment base offsets (shorts): ((rowblk*4 + s*2 + kh)*32 + ln)*8
  const int fA0 = (((wm * 2 + 0) * 4 + kh) * 32 + ln) * 8;
  const int fA1 = (((wm * 2 + 1) * 4 + kh) * 32 + ln) * 8;
  const int fB0 = (((wn * 2 + 0) * 4 + kh) * 32 + ln) * 8;
  const int fB1 = (((wn * 2 + 1) * 4 + kh) * 32 + ln) * 8;
  constexpr int SOFF = 2 * 32 * 8;   // s=1 group offset = 512 shorts

  stage_tile(Ab, sA[0], tid, 0);
  stage_tile(Bb, sB[0], tid, 0);
  __syncthreads();   // compiler drains vmcnt before s_barrier

  #pragma unroll 1
  for (int k0 = 0; k0 < K; k0 += 64) {
    // ---- even half: compute buf0, prefetch buf1
    {
      stage_tile(Ab, sA[1], tid, k0 + 32);
      stage_tile(Bb, sB[1], tid, k0 + 32);
      const short* sAc = sA[0];
      const short* sBc = sB[0];
      bf16x8 a0s0 = *(const bf16x8*)(sAc + fA0);
      bf16x8 a1s0 = *(const bf16x8*)(sAc + fA1);
      bf16x8 b0s0 = *(const bf16x8*)(sBc + fB0);
      bf16x8 b1s0 = *(const bf16x8*)(sBc + fB1);
      bf16x8 a0s1 = *(const bf16x8*)(sAc + fA0 + SOFF);
      bf16x8 a1s1 = *(const bf16x8*)(sAc + fA1 + SOFF);
      bf16x8 b0s1 = *(const bf16x8*)(sBc + fB0 + SOFF);
      bf16x8 b1s1 = *(const bf16x8*)(sBc + fB1 + SOFF);
      acc[0][0] = __builtin_amdgcn_mfma_f32_32x32x16_bf16(a0s0, b0s0, acc[0][0], 0, 0, 0);
      acc[0][1] = __builtin_amdgcn_mfma_f32_32x32x16_bf16(a0s0, b1s0, acc[0][1], 0, 0, 0);
      acc[1][0] = __builtin_amdgcn_mfma_f32_32x32x16_bf16(a1s0, b0s0, acc[1][0], 0, 0, 0);
      acc[1][1] = __builtin_amdgcn_mfma_f32_32x32x16_bf16(a1s0, b1s0, acc[1][1], 0, 0, 0);
      acc[0][0] = __builtin_amdgcn_mfma_f32_32x32x16_bf16(a0s1, b0s1, acc[0][0], 0, 0, 0);
      acc[0][1] = __builtin_amdgcn_mfma_f32_32x32x16_bf16(a0s1, b1s1, acc[0][1], 0, 0, 0);
      acc[1][0] = __builtin_amdgcn_mfma_f32_32x32x16_bf16(a1s1, b0s1, acc[1][0], 0, 0, 0);
      acc[1][1] = __builtin_amdgcn_mfma_f32_32x32x16_bf16(a1s1, b1s1, acc[1][1], 0, 0, 0);
      __syncthreads();
    }
    // ---- odd half: compute buf1, prefetch buf0 for next k0
    {
      if (k0 + 64 < K) {
        stage_tile(Ab, sA[0], tid, k0 + 64);
        stage_tile(Bb, sB[0], tid, k0 + 64);
      }
      const short* sAc = sA[1];
      const short* sBc = sB[1];
      bf16x8 a0s0 = *(const bf16x8*)(sAc + fA0);
      bf16x8 a1s0 = *(const bf16x8*)(sAc + fA1);
      bf16x8 b0s0 = *(const bf16x8*)(sBc + fB0);
      bf16x8 b1s0 = *(const bf16x8*)(sBc + fB1);
      bf16x8 a0s1 = *(const bf16x8*)(sAc + fA0 + SOFF);
      bf16x8 a1s1 = *(const bf16x8*)(sAc + fA1 + SOFF);
      bf16x8 b0s1 = *(const bf16x8*)(sBc + fB0 + SOFF);
      bf16x8 b1s1 = *(const bf16x8*)(sBc + fB1 + SOFF);
      acc[0][0] = __builtin_amdgcn_mfma_f32_32x32x16_bf16(a0s0, b0s0, acc[0][0], 0, 0, 0);
      acc[0][1] = __builtin_amdgcn_mfma_f32_32x32x16_bf16(a0s0, b1s0, acc[0][1], 0, 0, 0);
      acc[1][0] = __builtin_amdgcn_mfma_f32_32x32x16_bf16(a1s0, b0s0, acc[1][0], 0, 0, 0);
      acc[1][1] = __builtin_amdgcn_mfma_f32_32x32x16_bf16(a1s0, b1s0, acc[1][1], 0, 0, 0);
      acc[0][0] = __builtin_amdgcn_mfma_f32_32x32x16_bf16(a0s1, b0s1, acc[0][0], 0, 0, 0);
      acc[0][1] = __builtin_amdgcn_mfma_f32_32x32x16_bf16(a0s1, b1s1, acc[0][1], 0, 0, 0);
      acc[1][0] = __builtin_amdgcn_mfma_f32_32x32x16_bf16(a1s1, b0s1, acc[1][0], 0, 0, 0);
      acc[1][1] = __builtin_amdgcn_mfma_f32_32x32x16_bf16(a1s1, b1s1, acc[1][1], 0, 0, 0);
      __syncthreads();
    }
  }

  // Epilogue: 32x32 C/D layout: col = lane&31, row = (reg&3) + 8*(reg>>2) + 4*kh
  #pragma unroll
  for (int jb = 0; jb < 2; jb++) {
    const int col = n0 + wn * 64 + jb * 32 + ln;
    const float sc = wscale[col];
    #pragma unroll
    for (int ib = 0; ib < 2; ib++) {
      const int rbase = m0 + wm * 64 + ib * 32 + 4 * kh;
      #pragma unroll
      for (int r = 0; r < 16; r++) {
        const int row = rbase + (r & 3) + 8 * (r >> 2);
        C[(long)row * N + col] = acc[ib][jb][r] * sc;
      }
    }
  }
}

extern "C" void kernel_launch(void* const* d_in, const int* in_sizes, int n_in,
                              void* d_out, int out_size, void* d_ws, size_t ws_size,
                              hipStream_t stream) {
  const float* x   = (const float*)d_in[0];   // [4,2048,4096] fp32
  const float* wgt = (const float*)d_in[1];   // [4096,4096] fp32
  float* out = (float*)d_out;                 // [4,2048,4096] fp32

  // Workspace: A bf16 [M*K] | T bf16 [N*K] | wscale f32 [N]  (~96 MB)
  unsigned short* Aq = (unsigned short*)d_ws;
  unsigned short* Tq = Aq + (size_t)M * K;
  float* wscale = (float*)(Tq + (size_t)N * K);

  quant_fused_kernel<<<XBLOCKS + N, 256, 0, stream>>>(x, wgt, Aq, Tq, wscale);

  dim3 grid(N / 128, M / 128);
  gemm_bt_kernel<<<grid, 256, 0, stream>>>((const short*)Aq, (const short*)Tq,
                                           wscale, out);
}